// Round 7
// baseline (401.869 us; speedup 1.0000x reference)
//
#include <hip/hip_runtime.h>
#include <stdint.h>

// ---------------------------------------------------------------------------
// CausalSelfAttention: x[4,2048,1024] -> qkv -> flash attn -> proj
// Round 7: flash computes S^T = K*Q^T (operand swap, same fragments) so P^T
// lives in registers in exactly the B-fragment layout of mfma_16x16x16bf16_1k.
// PV = V^T * P^T with V^T A-frags as contiguous ds_read_b64 from lVT.
// => the entire P LDS round-trip (32 ds_write_b16 + 8 ds_read_b128 + lgkm
// serialization + 17KB lP) is deleted. 2-tile pairing, 1024 blocks (r3 grid).
// GEMMs unchanged from r6 (XCD swizzle + XOR-swizzled LDS).
// ---------------------------------------------------------------------------

typedef __attribute__((ext_vector_type(8))) short short8;   // 8 bf16 (4 VGPRs)
typedef __attribute__((ext_vector_type(4))) short short4v;  // 4 bf16 (2 VGPRs)
typedef __attribute__((ext_vector_type(4))) float floatx4;  // MFMA C/D frag
typedef __attribute__((ext_vector_type(2))) unsigned int uint2v;

#define AS1C(p) ((const __attribute__((address_space(1))) void*)(p))
#define AS3(p)  ((__attribute__((address_space(3))) void*)(p))

#define SC2F 0.18033688011f   // (1/sqrt(64)) * log2(e)

__device__ __forceinline__ unsigned short f2bf(float f) {
  unsigned int u = __builtin_bit_cast(unsigned int, f);
  u = (u + 0x7fffu + ((u >> 16) & 1u)) >> 16;   // RNE
  return (unsigned short)u;
}

// ---- fp32 -> bf16 elementwise (x4 vectorized) ----
__global__ void k_cvt(const float* __restrict__ in, unsigned short* __restrict__ out, int n4) {
  int i = blockIdx.x * blockDim.x + threadIdx.x;
  if (i < n4) {
    float4 v = ((const float4*)in)[i];
    ushort4 o;
    o.x = f2bf(v.x); o.y = f2bf(v.y); o.z = f2bf(v.z); o.w = f2bf(v.w);
    ((ushort4*)out)[i] = o;
  }
}

// ---- transpose fp32 [K][N] -> bf16 [N][K] (weights) ----
__global__ void k_tw(const float* __restrict__ in, unsigned short* __restrict__ out, int K, int N) {
  __shared__ float t[32][33];
  int n0 = blockIdx.x * 32, k0 = blockIdx.y * 32;
  int tx = threadIdx.x, ty = threadIdx.y;
#pragma unroll
  for (int i = 0; i < 4; i++)
    t[ty + 8 * i][tx] = in[(size_t)(k0 + ty + 8 * i) * N + n0 + tx];
  __syncthreads();
#pragma unroll
  for (int i = 0; i < 4; i++)
    out[(size_t)(n0 + ty + 8 * i) * K + k0 + tx] = f2bf(t[tx][ty + 8 * i]);
}

// ---- transpose V slice of qkv (bf16) -> VT[bh][d][t] ----
__global__ void k_tv(const unsigned short* __restrict__ qkv, unsigned short* __restrict__ vt) {
  __shared__ unsigned short t[32][33];
  int t0 = blockIdx.x * 32;
  int d0 = blockIdx.y * 32;
  int bh = blockIdx.z;
  int b = bh >> 4, h = bh & 15;
  int tx = threadIdx.x, ty = threadIdx.y;
#pragma unroll
  for (int i = 0; i < 4; i++)
    t[ty + 8 * i][tx] = qkv[(size_t)(b * 2048 + t0 + ty + 8 * i) * 3072 + 2048 + h * 64 + d0 + tx];
  __syncthreads();
#pragma unroll
  for (int i = 0; i < 4; i++)
    vt[(size_t)(bh * 64 + d0 + ty + 8 * i) * 2048 + t0 + tx] = t[tx][ty + 8 * i];
}

// ---- 128x128 bf16 GEMM, C = A[M,K] @ Bt[N,K]^T + bias, XOR-swizzled LDS,
// XCD-aware 1-D grid (by%8 == lin%8) ----
template <int OUT_F32>
__global__ __launch_bounds__(256)
void k_gemm(const unsigned short* __restrict__ A,
            const unsigned short* __restrict__ Bt,
            const float* __restrict__ bias,
            void* __restrict__ Cout, int M, int N, int K, int NX) {
  __shared__ unsigned short lA[128 * 64];
  __shared__ unsigned short lB[128 * 64];
  int lin = blockIdx.x;
  int xcd = lin & 7, idx = lin >> 3;
  int bx = idx % NX;
  int by = xcd + 8 * (idx / NX);
  int tid = threadIdx.x;
  int lane = tid & 63, wv = tid >> 6;
  int lc = lane & 15, quad = lane >> 4;
  int m0 = by * 128, n0 = bx * 128;
  int wm = (wv >> 1) * 64, wn = (wv & 1) * 64;
  int sw = lc & 7;

  floatx4 acc[4][4];
#pragma unroll
  for (int i = 0; i < 4; i++)
#pragma unroll
    for (int j = 0; j < 4; j++) acc[i][j] = (floatx4){0.f, 0.f, 0.f, 0.f};

  int srow = tid >> 3;
  int scol = (((tid & 7) ^ (srow & 7))) * 8;
  const unsigned short* gA = A + (size_t)(m0 + srow) * K + scol;
  const unsigned short* gB = Bt + (size_t)(n0 + srow) * K + scol;

  for (int k0 = 0; k0 < K; k0 += 64) {
#pragma unroll
    for (int c = 0; c < 4; c++) {
      __builtin_amdgcn_global_load_lds(AS1C(gA + (size_t)(32 * c) * K + k0),
                                       AS3(lA + (32 * c + 8 * wv) * 64), 16, 0, 0);
      __builtin_amdgcn_global_load_lds(AS1C(gB + (size_t)(32 * c) * K + k0),
                                       AS3(lB + (32 * c + 8 * wv) * 64), 16, 0, 0);
    }
    __syncthreads();
#pragma unroll
    for (int s = 0; s < 2; s++) {
      short8 af[4], bfr[4];
#pragma unroll
      for (int i = 0; i < 4; i++)
        af[i] = *(const short8*)(lA + (wm + i * 16 + lc) * 64 + (((s * 4 + quad) ^ sw) * 8));
#pragma unroll
      for (int j = 0; j < 4; j++)
        bfr[j] = *(const short8*)(lB + (wn + j * 16 + lc) * 64 + (((s * 4 + quad) ^ sw) * 8));
#pragma unroll
      for (int i = 0; i < 4; i++)
#pragma unroll
        for (int j = 0; j < 4; j++)
          acc[i][j] = __builtin_amdgcn_mfma_f32_16x16x32_bf16(af[i], bfr[j], acc[i][j], 0, 0, 0);
    }
    __syncthreads();
  }

  float bv[4];
#pragma unroll
  for (int j = 0; j < 4; j++) bv[j] = bias[n0 + wn + j * 16 + lc];
#pragma unroll
  for (int i = 0; i < 4; i++) {
#pragma unroll
    for (int j = 0; j < 4; j++) {
      float sc = (!OUT_F32 && (n0 + wn + j * 16) < 1024) ? SC2F : 1.0f;
#pragma unroll
      for (int r = 0; r < 4; r++) {
        size_t idx2 = (size_t)(m0 + wm + i * 16 + quad * 4 + r) * N + (n0 + wn + j * 16 + lc);
        float v = (acc[i][j][r] + bv[j]) * sc;
        if (OUT_F32) ((float*)Cout)[idx2] = v;
        else         ((unsigned short*)Cout)[idx2] = f2bf(v);
      }
    }
  }
}

// ---- flash attention, paired q-tiles (j, 31-j), register-resident P^T ----
__global__ __launch_bounds__(256, 4)
void k_flash(const unsigned short* __restrict__ qkv,
             const unsigned short* __restrict__ vt,
             unsigned short* __restrict__ y) {
  __shared__ unsigned short lK[64 * 64];
  __shared__ unsigned short lVT[64 * 64];
  int tid = threadIdx.x, lane = tid & 63, wv = tid >> 6;
  int lc = lane & 15, quad = lane >> 4;
  int sw = lc & 7;
  int j  = blockIdx.x;          // 0..15 pair index
  int bh = blockIdx.y;          // 0..63
  int b = bh >> 4, h = bh & 15;
  int qtA = j, qtB = 31 - j;
  int qrA = qtA * 64 + wv * 16;  // wave's 16-q strip (q = qr + lc)
  int qrB = qtB * 64 + wv * 16;

  // Q B-fragments: B[k=d][n=q] -> lane n=lc holds Q[q=qr+lc][d=quad*8+j]
  short8 qfA[2], qfB[2];
  {
    const unsigned short* qp = qkv + (size_t)(b * 2048 + qrA + lc) * 3072 + h * 64 + quad * 8;
    qfA[0] = *(const short8*)qp;
    qfA[1] = *(const short8*)(qp + 32);
  }
  {
    const unsigned short* qp = qkv + (size_t)(b * 2048 + qrB + lc) * 3072 + h * 64 + quad * 8;
    qfB[0] = *(const short8*)qp;
    qfB[1] = *(const short8*)(qp + 32);
  }

  // O^T accumulators: o[t][dt] C-layout col=lc=q, row=quad*4+r -> d=dt*16+quad*4+r
  float rsA = 0.f, rsB = 0.f;   // per-lane partial row-sum for q=lc (quad-partial)
  floatx4 oA[4], oB[4];
#pragma unroll
  for (int dt = 0; dt < 4; dt++) {
    oA[dt] = (floatx4){0.f, 0.f, 0.f, 0.f};
    oB[dt] = (floatx4){0.f, 0.f, 0.f, 0.f};
  }

  int srow = tid >> 3;
  int scol = ((tid & 7) ^ (srow & 7)) * 8;
  const unsigned short* gK = qkv + (size_t)(b * 2048 + srow) * 3072 + 1024 + h * 64 + scol;
  const unsigned short* gV = vt + (size_t)(bh * 64 + srow) * 2048 + scol;

  int nt = qtB + 1;

  for (int kv = 0; kv < nt; kv++) {
    int kv0 = kv * 64;
#pragma unroll
    for (int c = 0; c < 2; c++) {
      __builtin_amdgcn_global_load_lds(AS1C(gK + (size_t)(kv0 + 32 * c) * 3072),
                                       AS3(lK + (32 * c + 8 * wv) * 64), 16, 0, 0);
      __builtin_amdgcn_global_load_lds(AS1C(gV + (size_t)(32 * c) * 2048 + kv0),
                                       AS3(lVT + (32 * c + 8 * wv) * 64), 16, 0, 0);
    }
    __syncthreads();

    bool withA = (kv <= qtA);
    bool diagA = (kv == qtA), diagB = (kv == qtB);

    // ---- S^T = K Q^T per 16-kv subtile; P^T packed to bf16 in registers ----
    short4v pfB[4], pfA[4];
#pragma unroll
    for (int n = 0; n < 4; n++) {
      // K A-frag: A[m=kv][k=d] -> lane m=lc holds K[kv0+n*16+lc][d=quad*8+j]
      short8 kf0 = *(const short8*)(lK + (n * 16 + lc) * 64 + ((quad ^ sw) * 8));
      short8 kf1 = *(const short8*)(lK + (n * 16 + lc) * 64 + (((4 + quad) ^ sw) * 8));
      {
        floatx4 s = (floatx4){0.f, 0.f, 0.f, 0.f};
        s = __builtin_amdgcn_mfma_f32_16x16x32_bf16(kf0, qfB[0], s, 0, 0, 0);
        s = __builtin_amdgcn_mfma_f32_16x16x32_bf16(kf1, qfB[1], s, 0, 0, 0);
        // lane holds S^T[kv=n*16+quad*4+r][q=lc]
        unsigned pu[4];
#pragma unroll
        for (int r = 0; r < 4; r++) {
          float arg = s[r];
          if (diagB && (n * 16 + quad * 4 + r > wv * 16 + lc)) arg = -__builtin_inff();
          float p = __builtin_amdgcn_exp2f(arg);
          rsB += p;
          pu[r] = __builtin_bit_cast(unsigned, p);
        }
        uint2v pk = {(pu[0] >> 16) | (pu[1] & 0xffff0000u),
                     (pu[2] >> 16) | (pu[3] & 0xffff0000u)};
        pfB[n] = __builtin_bit_cast(short4v, pk);
      }
      if (withA) {
        floatx4 s = (floatx4){0.f, 0.f, 0.f, 0.f};
        s = __builtin_amdgcn_mfma_f32_16x16x32_bf16(kf0, qfA[0], s, 0, 0, 0);
        s = __builtin_amdgcn_mfma_f32_16x16x32_bf16(kf1, qfA[1], s, 0, 0, 0);
        unsigned pu[4];
#pragma unroll
        for (int r = 0; r < 4; r++) {
          float arg = s[r];
          if (diagA && (n * 16 + quad * 4 + r > wv * 16 + lc)) arg = -__builtin_inff();
          float p = __builtin_amdgcn_exp2f(arg);
          rsA += p;
          pu[r] = __builtin_bit_cast(unsigned, p);
        }
        uint2v pk = {(pu[0] >> 16) | (pu[1] & 0xffff0000u),
                     (pu[2] >> 16) | (pu[3] & 0xffff0000u)};
        pfA[n] = __builtin_bit_cast(short4v, pk);
      }
    }

    // ---- O^T += V^T P^T (K=16 MFMA; A=V^T frag b64 from lVT, B=P^T in regs) ----
#pragma unroll
    for (int n = 0; n < 4; n++) {
#pragma unroll
      for (int dt = 0; dt < 4; dt++) {
        // A[m=d][k=kv]: lane m=lc -> d=dt*16+lc, kv=n*16+quad*4+j (j=0..3)
        short4v vf = *(const short4v*)(lVT + (dt * 16 + lc) * 64 +
                                       (((2 * n + (quad >> 1)) ^ sw) * 8) + (quad & 1) * 4);
        oB[dt] = __builtin_amdgcn_mfma_f32_16x16x16bf16_1k(vf, pfB[n], oB[dt], 0, 0, 0);
        if (withA)
          oA[dt] = __builtin_amdgcn_mfma_f32_16x16x16bf16_1k(vf, pfA[n], oA[dt], 0, 0, 0);
      }
    }
    __syncthreads();   // protect lK/lVT before next stage
  }

  // ---- epilogue: reduce row-sums across quads (q=lc fixed per lane) ----
  rsA += __shfl_xor(rsA, 16); rsA += __shfl_xor(rsA, 32);
  rsB += __shfl_xor(rsB, 16); rsB += __shfl_xor(rsB, 32);
  float invA = 1.0f / rsA, invB = 1.0f / rsB;

  // store: y[q][h*64 + dt*16 + quad*4 + r], q = qr + lc ; 8B packed stores
#pragma unroll
  for (int dt = 0; dt < 4; dt++) {
    ushort4 sA, sB;
    sA.x = f2bf(oA[dt][0] * invA); sA.y = f2bf(oA[dt][1] * invA);
    sA.z = f2bf(oA[dt][2] * invA); sA.w = f2bf(oA[dt][3] * invA);
    sB.x = f2bf(oB[dt][0] * invB); sB.y = f2bf(oB[dt][1] * invB);
    sB.z = f2bf(oB[dt][2] * invB); sB.w = f2bf(oB[dt][3] * invB);
    *(ushort4*)(y + (size_t)(b * 2048 + qrA + lc) * 1024 + h * 64 + dt * 16 + quad * 4) = sA;
    *(ushort4*)(y + (size_t)(b * 2048 + qrB + lc) * 1024 + h * 64 + dt * 16 + quad * 4) = sB;
  }
}

extern "C" void kernel_launch(void* const* d_in, const int* in_sizes, int n_in,
                              void* d_out, int out_size, void* d_ws, size_t ws_size,
                              hipStream_t stream) {
  const float* x      = (const float*)d_in[0];
  const float* W_attn = (const float*)d_in[1];
  const float* b_attn = (const float*)d_in[2];
  const float* W_proj = (const float*)d_in[3];
  const float* b_proj = (const float*)d_in[4];

  char* ws = (char*)d_ws;
  unsigned short* xb     = (unsigned short*)ws;                    // 16.8 MB (reused as y)
  unsigned short* wattnT = (unsigned short*)(ws + 16777216);       // 6.3 MB
  unsigned short* wprojT = (unsigned short*)(ws + 23068672);       // 2.1 MB
  unsigned short* qkv    = (unsigned short*)(ws + 25165824);       // 50.3 MB
  unsigned short* vt     = (unsigned short*)(ws + 75497472);       // 16.8 MB -> total 92.3 MB
  unsigned short* y      = xb;   // xb dead after QKV GEMM

  k_cvt<<<8192, 256, 0, stream>>>(x, xb, 8388608 / 4);
  k_tw<<<dim3(96, 32), dim3(32, 8), 0, stream>>>(W_attn, wattnT, 1024, 3072);
  k_tw<<<dim3(32, 32), dim3(32, 8), 0, stream>>>(W_proj, wprojT, 1024, 1024);
  k_gemm<0><<<24 * 64, 256, 0, stream>>>(xb, wattnT, b_attn, qkv, 8192, 3072, 1024, 24);
  k_tv<<<dim3(64, 2, 64), dim3(32, 8), 0, stream>>>(qkv, vt);
  k_flash<<<dim3(16, 64), 256, 0, stream>>>(qkv, vt, y);
  k_gemm<1><<<8 * 64, 256, 0, stream>>>(y, wprojT, b_proj, d_out, 8192, 1024, 1024, 8);
}